// Round 2
// baseline (717.922 us; speedup 1.0000x reference)
//
#include <hip/hip_runtime.h>
#include <cstddef>

#define LEAKY 0.2f
#define EPS_DEN 1e-16f

// ---------------------------------------------------------------------------
// CSR build: histogram -> scan -> scatter (rebuilt every call; no static state)
// ---------------------------------------------------------------------------
__global__ void hist_kernel(const int* __restrict__ dst, int* __restrict__ counts, int E) {
    int i = blockIdx.x * blockDim.x + threadIdx.x;
    if (i < E) atomicAdd(&counts[dst[i]], 1);
}

__global__ void scan_kernel(const int* __restrict__ counts, int* __restrict__ offs,
                            int* __restrict__ cursor, int N) {
    __shared__ int s[256];
    __shared__ int carry_s;
    int t = threadIdx.x;
    if (t == 0) carry_s = 0;
    __syncthreads();
    for (int base = 0; base < N; base += 256) {
        int i = base + t;
        int v = (i < N) ? counts[i] : 0;
        s[t] = v;
        __syncthreads();
#pragma unroll
        for (int st = 1; st < 256; st <<= 1) {
            int add = (t >= st) ? s[t - st] : 0;
            __syncthreads();
            s[t] += add;
            __syncthreads();
        }
        int carry = carry_s;
        int excl = carry + s[t] - v;   // exclusive prefix
        if (i < N) { offs[i] = excl; cursor[i] = excl; }
        __syncthreads();
        if (t == 255) carry_s = carry + s[255];
        __syncthreads();
    }
    if (t == 0) offs[N] = carry_s;
}

__global__ void scatter_kernel(const int* __restrict__ src, const int* __restrict__ dst,
                               int* __restrict__ cursor, int* __restrict__ csrc,
                               int* __restrict__ cdst, int E) {
    int i = blockIdx.x * blockDim.x + threadIdx.x;
    if (i < E) {
        int d = dst[i];
        int pos = atomicAdd(&cursor[d], 1);
        csrc[pos] = src[i];
        cdst[pos] = d;
    }
}

// ---------------------------------------------------------------------------
// fp32 SMEM GEMM: C[M,N] = A[M,K] @ B[K,N].  BM=128 BN=64 BK=16, 256 thr, 8x4/thr
// ---------------------------------------------------------------------------
__global__ __launch_bounds__(256) void sgemm_kernel(const float* __restrict__ A,
                                                    const float* __restrict__ B,
                                                    float* __restrict__ C,
                                                    int M, int N, int K) {
    constexpr int BM = 128, BN = 64, BK = 16, TM = 8, TN = 4;
    __shared__ float sA[BK][BM + 4];
    __shared__ float sB[BK][BN];
    int tx = threadIdx.x % (BN / TN);   // 0..15
    int ty = threadIdx.x / (BN / TN);   // 0..15
    int m0 = blockIdx.y * BM, n0 = blockIdx.x * BN;
    float acc[TM][TN] = {};
    int ak = threadIdx.x % BK;          // 0..15
    int am = threadIdx.x / BK;          // 0..15
    int bn = threadIdx.x % BN;          // 0..63
    int bk = threadIdx.x / BN;          // 0..3
    for (int k0 = 0; k0 < K; k0 += BK) {
#pragma unroll
        for (int i = 0; i < BM / 16; i++) {        // 8 rows per thread
            int m = am + i * 16;
            int gm = m0 + m;
            float v = 0.f;
            if (gm < M) v = A[(size_t)gm * K + k0 + ak];
            sA[ak][m] = v;
        }
#pragma unroll
        for (int i = 0; i < BK / 4; i++) {         // 4 k-rows per thread
            int k = bk + i * 4;
            sB[k][bn] = B[(size_t)(k0 + k) * N + n0 + bn];
        }
        __syncthreads();
#pragma unroll
        for (int k = 0; k < BK; k++) {
            float a[TM], b[TN];
#pragma unroll
            for (int i = 0; i < TM; i++) a[i] = sA[k][ty * TM + i];
#pragma unroll
            for (int j = 0; j < TN; j++) b[j] = sB[k][tx * TN + j];
#pragma unroll
            for (int i = 0; i < TM; i++)
#pragma unroll
                for (int j = 0; j < TN; j++) acc[i][j] += a[i] * b[j];
        }
        __syncthreads();
    }
#pragma unroll
    for (int i = 0; i < TM; i++) {
        int gm = m0 + ty * TM + i;
        if (gm >= M) continue;
#pragma unroll
        for (int j = 0; j < TN; j++)
            C[(size_t)gm * N + n0 + tx * TN + j] = acc[i][j];
    }
}

// ---------------------------------------------------------------------------
// attention logits: al_s[n,h] = sum_c h[n,h,c]*a_src[h,c];  H=4,C=128 (F=512)
// one wave per node, 4 nodes / 256-thread block
// ---------------------------------------------------------------------------
__global__ void al_h4_kernel(const float* __restrict__ h, const float* __restrict__ a_src,
                             const float* __restrict__ a_dst, float* __restrict__ als,
                             float* __restrict__ ald, int N) {
    int wave = threadIdx.x >> 6, lane = threadIdx.x & 63;
    int n = blockIdx.x * 4 + wave;
    if (n >= N) return;
    const float* row = h + (size_t)n * 512;
    float ps[4] = {0, 0, 0, 0}, pd[4] = {0, 0, 0, 0};
#pragma unroll
    for (int k = 0; k < 8; k++) {
        int f = k * 64 + lane;
        float v = row[f];
        ps[k >> 1] += v * a_src[f];
        pd[k >> 1] += v * a_dst[f];
    }
#pragma unroll
    for (int off = 32; off; off >>= 1) {
#pragma unroll
        for (int hd = 0; hd < 4; hd++) {
            ps[hd] += __shfl_down(ps[hd], off);
            pd[hd] += __shfl_down(pd[hd], off);
        }
    }
    if (lane == 0) {
#pragma unroll
        for (int hd = 0; hd < 4; hd++) {
            als[n * 4 + hd] = ps[hd];
            ald[n * 4 + hd] = pd[hd];
        }
    }
}

// H=1, C=128
__global__ void al_h1_kernel(const float* __restrict__ h, const float* __restrict__ a_src,
                             const float* __restrict__ a_dst, float* __restrict__ als,
                             float* __restrict__ ald, int N) {
    int wave = threadIdx.x >> 6, lane = threadIdx.x & 63;
    int n = blockIdx.x * 4 + wave;
    if (n >= N) return;
    const float* row = h + (size_t)n * 128;
    float v0 = row[lane], v1 = row[lane + 64];
    float ps = v0 * a_src[lane] + v1 * a_src[lane + 64];
    float pd = v0 * a_dst[lane] + v1 * a_dst[lane + 64];
#pragma unroll
    for (int off = 32; off; off >>= 1) {
        ps += __shfl_down(ps, off);
        pd += __shfl_down(pd, off);
    }
    if (lane == 0) { als[n] = ps; ald[n] = pd; }
}

// ---------------------------------------------------------------------------
// per-edge attention logit e (leaky-relu), CSR slot order
// ---------------------------------------------------------------------------
template <int H>
__global__ void ecomp_kernel(const int* __restrict__ csrc, const int* __restrict__ cdst,
                             const float* __restrict__ als, const float* __restrict__ ald,
                             float* __restrict__ ebuf, int E) {
    int idx = blockIdx.x * blockDim.x + threadIdx.x;
    if (idx >= E * H) return;
    int slot = idx / H, hd = idx % H;
    float e = als[csrc[slot] * H + hd] + ald[cdst[slot] * H + hd];
    ebuf[idx] = e > 0.f ? e : LEAKY * e;
}

// ---------------------------------------------------------------------------
// Fused segment-softmax + aggregate (online softmax), one block per dst node.
// Self-loop handled implicitly as the first element.
// ---------------------------------------------------------------------------
template <int H, int C, int FPT, bool DO_ELU>
__global__ void gat_aggregate_kernel(const float* __restrict__ h, const float* __restrict__ ebuf,
                                     const int* __restrict__ csrc, const int* __restrict__ offs,
                                     const float* __restrict__ als, const float* __restrict__ ald,
                                     const float* __restrict__ bias, float* __restrict__ outp,
                                     int N) {
    constexpr int F = H * C;
    constexpr int NT = F / FPT;  // block size
    constexpr int CH = 128;
    __shared__ int sSrc[CH];
    __shared__ float sE[CH * H];
    int n = blockIdx.x;
    int t = threadIdx.x;
    float m[FPT], d[FPT], acc[FPT];
    int f[FPT], hd[FPT];
    const float* selfrow = h + (size_t)n * F;
#pragma unroll
    for (int i = 0; i < FPT; i++) {
        f[i] = t + i * NT;
        hd[i] = f[i] / C;
        float es = als[n * H + hd[i]] + ald[n * H + hd[i]];
        es = es > 0.f ? es : LEAKY * es;
        m[i] = es;                   // self-loop is the first softmax element
        d[i] = 1.0f;
        acc[i] = selfrow[f[i]];
    }
    int beg = offs[n], end = offs[n + 1];
    for (int base = beg; base < end; base += CH) {
        int len = min(CH, end - base);
        __syncthreads();
        for (int c = t; c < len; c += NT) sSrc[c] = csrc[base + c];
        for (int c = t; c < len * H; c += NT) sE[c] = ebuf[base * H + c];
        __syncthreads();
        for (int c = 0; c < len; c++) {
            int s = sSrc[c];
            const float* srow = h + (size_t)s * F;
#pragma unroll
            for (int i = 0; i < FPT; i++) {
                float e = sE[c * H + hd[i]];
                float nm = fmaxf(m[i], e);
                float sc = __expf(m[i] - nm);
                float p = __expf(e - nm);
                float x = srow[f[i]];
                d[i] = d[i] * sc + p;
                acc[i] = acc[i] * sc + p * x;
                m[i] = nm;
            }
        }
    }
#pragma unroll
    for (int i = 0; i < FPT; i++) {
        float o = acc[i] / (d[i] + EPS_DEN) + bias[f[i]];
        if (DO_ELU) o = o > 0.f ? o : (__expf(o) - 1.0f);  // ELU: e^o - 1 (__expf IS e^x)
        outp[(size_t)n * F + f[i]] = o;
    }
}

// ---------------------------------------------------------------------------
// classifier: out = relu(emb @ Wc1 + bc1) @ Wc2 + bc2 ; one wave per node
// ---------------------------------------------------------------------------
__global__ void classifier_kernel(const float* __restrict__ emb, const float* __restrict__ Wc1,
                                  const float* __restrict__ bc1, const float* __restrict__ Wc2,
                                  const float* __restrict__ bc2, float* __restrict__ out, int N) {
    int wave = threadIdx.x >> 6, lane = threadIdx.x & 63;
    int n = blockIdx.x * 4 + wave;
    if (n >= N) return;
    const float* row = emb + (size_t)n * 128;
    float acc = bc1[lane];
#pragma unroll 4
    for (int k = 0; k < 128; k++) acc += row[k] * Wc1[k * 64 + lane];
    acc = fmaxf(acc, 0.f);
    float o0 = acc * Wc2[lane * 2 + 0];
    float o1 = acc * Wc2[lane * 2 + 1];
#pragma unroll
    for (int off = 32; off; off >>= 1) {
        o0 += __shfl_down(o0, off);
        o1 += __shfl_down(o1, off);
    }
    if (lane == 0) {
        out[n * 2 + 0] = o0 + bc2[0];
        out[n * 2 + 1] = o1 + bc2[1];
    }
}

// ---------------------------------------------------------------------------
extern "C" void kernel_launch(void* const* d_in, const int* in_sizes, int n_in,
                              void* d_out, int out_size, void* d_ws, size_t ws_size,
                              hipStream_t stream) {
    const float* x      = (const float*)d_in[0];
    const int*   ei     = (const int*)d_in[1];
    const float* W1     = (const float*)d_in[2];
    const float* a1s    = (const float*)d_in[3];
    const float* a1d    = (const float*)d_in[4];
    const float* b1     = (const float*)d_in[5];
    const float* W2     = (const float*)d_in[6];
    const float* a2s    = (const float*)d_in[7];
    const float* a2d    = (const float*)d_in[8];
    const float* b2     = (const float*)d_in[9];
    const float* W3     = (const float*)d_in[10];
    const float* a3s    = (const float*)d_in[11];
    const float* a3d    = (const float*)d_in[12];
    const float* b3     = (const float*)d_in[13];
    const float* Wc1    = (const float*)d_in[14];
    const float* bc1    = (const float*)d_in[15];
    const float* Wc2    = (const float*)d_in[16];
    const float* bc2    = (const float*)d_in[17];

    const int N = in_sizes[0] / 256;       // 10000
    const int E = in_sizes[1] / 2;         // 320000
    const int F = 512;                     // 4 heads x 128

    const int* src = ei;
    const int* dst = ei + E;

    // workspace carve-up (bytes, 256-aligned)
    auto align = [](size_t o) { return (o + 255) & ~(size_t)255; };
    size_t o = 0;
    size_t o_G    = o; o = align(o + (size_t)N * F * 4);      // GEMM output h
    size_t o_Act  = o; o = align(o + (size_t)N * F * 4);      // activations
    size_t o_als  = o; o = align(o + (size_t)N * 4 * 4);
    size_t o_ald  = o; o = align(o + (size_t)N * 4 * 4);
    size_t o_cnt  = o; o = align(o + (size_t)N * 4);          // counts / cursor
    size_t o_off  = o; o = align(o + (size_t)(N + 1) * 4);
    size_t o_csrc = o; o = align(o + (size_t)E * 4);
    size_t o_cdst = o; o = align(o + (size_t)E * 4);
    size_t o_ebuf = o; o = align(o + (size_t)E * 4 * 4);
    (void)ws_size;

    char* ws = (char*)d_ws;
    float* bufG   = (float*)(ws + o_G);
    float* bufAct = (float*)(ws + o_Act);
    float* als    = (float*)(ws + o_als);
    float* ald    = (float*)(ws + o_ald);
    int*   cnt    = (int*)(ws + o_cnt);
    int*   offs   = (int*)(ws + o_off);
    int*   csrc   = (int*)(ws + o_csrc);
    int*   cdst   = (int*)(ws + o_cdst);
    float* ebuf   = (float*)(ws + o_ebuf);

    float* outp = (float*)d_out;                 // [N,2]
    float* emb  = (float*)d_out + (size_t)N * 2; // [N,128]

    // ---- CSR build ----
    hipMemsetAsync(cnt, 0, (size_t)N * 4, stream);
    int eb = (E + 255) / 256;
    hipLaunchKernelGGL(hist_kernel, dim3(eb), dim3(256), 0, stream, dst, cnt, E);
    hipLaunchKernelGGL(scan_kernel, dim3(1), dim3(256), 0, stream, cnt, offs, cnt, N);
    hipLaunchKernelGGL(scatter_kernel, dim3(eb), dim3(256), 0, stream, src, dst, cnt, csrc, cdst, E);

    int nb4 = (N + 3) / 4;
    int gy  = (N + 127) / 128;   // sgemm grid y (BM=128)

    // ---- layer 1: x[ N,256 ] @ W1[256,512] ----
    hipLaunchKernelGGL(sgemm_kernel, dim3(512 / 64, gy), dim3(256), 0, stream, x, W1, bufG, N, 512, 256);
    hipLaunchKernelGGL(al_h4_kernel, dim3(nb4), dim3(256), 0, stream, bufG, a1s, a1d, als, ald, N);
    hipLaunchKernelGGL((ecomp_kernel<4>), dim3((E * 4 + 255) / 256), dim3(256), 0, stream,
                       csrc, cdst, als, ald, ebuf, E);
    hipLaunchKernelGGL((gat_aggregate_kernel<4, 128, 2, true>), dim3(N), dim3(256), 0, stream,
                       bufG, ebuf, csrc, offs, als, ald, b1, bufAct, N);

    // ---- layer 2: act[N,512] @ W2[512,512] ----
    hipLaunchKernelGGL(sgemm_kernel, dim3(512 / 64, gy), dim3(256), 0, stream, bufAct, W2, bufG, N, 512, 512);
    hipLaunchKernelGGL(al_h4_kernel, dim3(nb4), dim3(256), 0, stream, bufG, a2s, a2d, als, ald, N);
    hipLaunchKernelGGL((ecomp_kernel<4>), dim3((E * 4 + 255) / 256), dim3(256), 0, stream,
                       csrc, cdst, als, ald, ebuf, E);
    hipLaunchKernelGGL((gat_aggregate_kernel<4, 128, 2, true>), dim3(N), dim3(256), 0, stream,
                       bufG, ebuf, csrc, offs, als, ald, b2, bufAct, N);

    // ---- layer 3: act[N,512] @ W3[512,128], 1 head, no ELU -> embeddings ----
    hipLaunchKernelGGL(sgemm_kernel, dim3(128 / 64, gy), dim3(256), 0, stream, bufAct, W3, bufG, N, 128, 512);
    hipLaunchKernelGGL(al_h1_kernel, dim3(nb4), dim3(256), 0, stream, bufG, a3s, a3d, als, ald, N);
    hipLaunchKernelGGL((ecomp_kernel<1>), dim3((E + 255) / 256), dim3(256), 0, stream,
                       csrc, cdst, als, ald, ebuf, E);
    hipLaunchKernelGGL((gat_aggregate_kernel<1, 128, 1, false>), dim3(N), dim3(128), 0, stream,
                       bufG, ebuf, csrc, offs, als, ald, b3, emb, N);

    // ---- classifier ----
    hipLaunchKernelGGL(classifier_kernel, dim3(nb4), dim3(256), 0, stream,
                       emb, Wc1, bc1, Wc2, bc2, outp, N);
}

// Round 3
// 527.690 us; speedup vs baseline: 1.3605x; 1.3605x over previous
//
#include <hip/hip_runtime.h>
#include <cstddef>

#define LEAKY 0.2f
#define EPS_DEN 1e-16f

typedef short bf8_t __attribute__((ext_vector_type(8)));   // 8 bf16 in 4 VGPRs
typedef float f4_t __attribute__((ext_vector_type(4)));

__device__ __forceinline__ unsigned short f2bf(float f) {   // RNE
    unsigned u = __float_as_uint(f);
    unsigned r = (u + 0x7fffu + ((u >> 16) & 1u)) >> 16;
    return (unsigned short)r;
}
__device__ __forceinline__ float bf2f(unsigned short h) {
    return __uint_as_float(((unsigned)h) << 16);
}

// ---------------------------------------------------------------------------
// CSR build: histogram -> scan -> scatter
// ---------------------------------------------------------------------------
__global__ void hist_kernel(const int* __restrict__ dst, int* __restrict__ counts, int E) {
    int i = blockIdx.x * blockDim.x + threadIdx.x;
    if (i < E) atomicAdd(&counts[dst[i]], 1);
}

__global__ void scan_kernel(const int* __restrict__ counts, int* __restrict__ offs,
                            int* __restrict__ cursor, int N) {
    __shared__ int s[256];
    __shared__ int carry_s;
    int t = threadIdx.x;
    if (t == 0) carry_s = 0;
    __syncthreads();
    for (int base = 0; base < N; base += 256) {
        int i = base + t;
        int v = (i < N) ? counts[i] : 0;
        s[t] = v;
        __syncthreads();
#pragma unroll
        for (int st = 1; st < 256; st <<= 1) {
            int add = (t >= st) ? s[t - st] : 0;
            __syncthreads();
            s[t] += add;
            __syncthreads();
        }
        int carry = carry_s;
        int excl = carry + s[t] - v;
        if (i < N) { offs[i] = excl; cursor[i] = excl; }
        __syncthreads();
        if (t == 255) carry_s = carry + s[255];
        __syncthreads();
    }
    if (t == 0) offs[N] = carry_s;
}

__global__ void scatter_kernel(const int* __restrict__ src, const int* __restrict__ dst,
                               int* __restrict__ cursor, int* __restrict__ csrc,
                               int* __restrict__ cdst, int E) {
    int i = blockIdx.x * blockDim.x + threadIdx.x;
    if (i < E) {
        int d = dst[i];
        int pos = atomicAdd(&cursor[d], 1);
        csrc[pos] = src[i];
        cdst[pos] = d;
    }
}

// ---------------------------------------------------------------------------
// split fp32 -> bf16 hi + bf16 lo (elementwise)
// ---------------------------------------------------------------------------
__global__ void split_kernel(const float* __restrict__ in, unsigned short* __restrict__ hi,
                             unsigned short* __restrict__ lo, int len) {
    int i = blockIdx.x * blockDim.x + threadIdx.x;
    if (i >= len) return;
    float v = in[i];
    unsigned short h = f2bf(v);
    hi[i] = h;
    lo[i] = f2bf(v - bf2f(h));
}

// W [K,N] fp32  ->  WT_hi/lo [N,K] bf16 (transpose + split)
__global__ void wsplit_kernel(const float* __restrict__ W, unsigned short* __restrict__ hi,
                              unsigned short* __restrict__ lo, int K, int N) {
    int idx = blockIdx.x * blockDim.x + threadIdx.x;
    if (idx >= K * N) return;
    int n = idx / K, k = idx % K;          // consecutive threads -> consecutive k (coalesced out)
    float v = W[(size_t)k * N + n];
    unsigned short h = f2bf(v);
    hi[idx] = h;
    lo[idx] = f2bf(v - bf2f(h));
}

// ---------------------------------------------------------------------------
// MFMA GEMM (split-bf16, 3 passes): C[M,N] = (Ahi+Alo) @ (Bhi+Blo)^T(stored as BT[N,K])
// m97 structure: 128x128 tile, BK=32, 16x16x32 bf16 MFMA, 4 waves, 4x4 tiles/wave,
// global_load_lds width 16.  K % 32 == 0, N % 128 == 0; M edge clamped.
// ---------------------------------------------------------------------------
__global__ __launch_bounds__(256) void mfma_gemm_kernel(
    const unsigned short* __restrict__ Ahi, const unsigned short* __restrict__ Alo,
    const unsigned short* __restrict__ BThi, const unsigned short* __restrict__ BTlo,
    float* __restrict__ C, int M, int N, int K) {
    constexpr int BK = 32;
    __shared__ __align__(16) unsigned short sA[128 * BK];   // [m][k], 8 KB
    __shared__ __align__(16) unsigned short sB[128 * BK];   // [n][k], 8 KB
    int t = threadIdx.x;
    int w = t >> 6, lane = t & 63;
    int quad = lane >> 4, low = lane & 15;
    int m0 = blockIdx.y * 128, n0 = blockIdx.x * 128;
    int wm = (w & 1) * 64, wn = (w >> 1) * 64;

    f4_t acc[4][4];
#pragma unroll
    for (int i = 0; i < 4; i++)
#pragma unroll
        for (int j = 0; j < 4; j++) acc[i][j] = (f4_t){0.f, 0.f, 0.f, 0.f};

    int srow = lane >> 2;     // 0..15 (staging row within 16-row chunk)
    int schunk = lane & 3;    // 0..3  (16B chunk within 64B row)

    const unsigned short* Ap[3] = {Ahi, Ahi, Alo};
    const unsigned short* Bp[3] = {BThi, BTlo, BThi};

    for (int pass = 0; pass < 3; pass++) {
        const unsigned short* A = Ap[pass];
        const unsigned short* B = Bp[pass];
        for (int k0 = 0; k0 < K; k0 += BK) {
            __syncthreads();   // previous tile fully consumed
#pragma unroll
            for (int inst = 0; inst < 2; inst++) {
                int r = w * 32 + inst * 16 + srow;
                int gm = m0 + r;
                if (gm >= M) gm = M - 1;
                const void* g = (const void*)(A + (size_t)gm * K + k0 + schunk * 8);
                void* l = (void*)((char*)sA + (size_t)(w * 2048 + inst * 1024));
                __builtin_amdgcn_global_load_lds((const __attribute__((address_space(1))) void*)g,
                                                 (__attribute__((address_space(3))) void*)l, 16, 0, 0);
            }
#pragma unroll
            for (int inst = 0; inst < 2; inst++) {
                int r = w * 32 + inst * 16 + srow;
                int gn = n0 + r;
                const void* g = (const void*)(B + (size_t)gn * K + k0 + schunk * 8);
                void* l = (void*)((char*)sB + (size_t)(w * 2048 + inst * 1024));
                __builtin_amdgcn_global_load_lds((const __attribute__((address_space(1))) void*)g,
                                                 (__attribute__((address_space(3))) void*)l, 16, 0, 0);
            }
            __syncthreads();   // drains vmcnt (compiler emits waitcnt before barrier)

            bf8_t af[4], bf[4];
#pragma unroll
            for (int i = 0; i < 4; i++) {
                int row = wm + i * 16 + low;
                af[i] = *(const bf8_t*)&sA[row * BK + quad * 8];
            }
#pragma unroll
            for (int j = 0; j < 4; j++) {
                int row = wn + j * 16 + low;
                bf[j] = *(const bf8_t*)&sB[row * BK + quad * 8];
            }
#pragma unroll
            for (int i = 0; i < 4; i++)
#pragma unroll
                for (int j = 0; j < 4; j++)
                    acc[i][j] = __builtin_amdgcn_mfma_f32_16x16x32_bf16(af[i], bf[j], acc[i][j], 0, 0, 0);
        }
    }

    // C/D layout: col = lane&15, row = quad*4 + reg   [m89/m91 verified]
#pragma unroll
    for (int i = 0; i < 4; i++) {
#pragma unroll
        for (int r = 0; r < 4; r++) {
            int gm = m0 + wm + i * 16 + quad * 4 + r;
            if (gm >= M) continue;
#pragma unroll
            for (int j = 0; j < 4; j++) {
                int gn = n0 + wn + j * 16 + low;
                C[(size_t)gm * N + gn] = acc[i][j][r];
            }
        }
    }
}

// ---------------------------------------------------------------------------
// attention logits
// ---------------------------------------------------------------------------
__global__ void al_h4_kernel(const float* __restrict__ h, const float* __restrict__ a_src,
                             const float* __restrict__ a_dst, float* __restrict__ als,
                             float* __restrict__ ald, int N) {
    int wave = threadIdx.x >> 6, lane = threadIdx.x & 63;
    int n = blockIdx.x * 4 + wave;
    if (n >= N) return;
    const float* row = h + (size_t)n * 512;
    float ps[4] = {0, 0, 0, 0}, pd[4] = {0, 0, 0, 0};
#pragma unroll
    for (int k = 0; k < 8; k++) {
        int f = k * 64 + lane;
        float v = row[f];
        ps[k >> 1] += v * a_src[f];
        pd[k >> 1] += v * a_dst[f];
    }
#pragma unroll
    for (int off = 32; off; off >>= 1) {
#pragma unroll
        for (int hd = 0; hd < 4; hd++) {
            ps[hd] += __shfl_down(ps[hd], off);
            pd[hd] += __shfl_down(pd[hd], off);
        }
    }
    if (lane == 0) {
#pragma unroll
        for (int hd = 0; hd < 4; hd++) {
            als[n * 4 + hd] = ps[hd];
            ald[n * 4 + hd] = pd[hd];
        }
    }
}

__global__ void al_h1_kernel(const float* __restrict__ h, const float* __restrict__ a_src,
                             const float* __restrict__ a_dst, float* __restrict__ als,
                             float* __restrict__ ald, int N) {
    int wave = threadIdx.x >> 6, lane = threadIdx.x & 63;
    int n = blockIdx.x * 4 + wave;
    if (n >= N) return;
    const float* row = h + (size_t)n * 128;
    float v0 = row[lane], v1 = row[lane + 64];
    float ps = v0 * a_src[lane] + v1 * a_src[lane + 64];
    float pd = v0 * a_dst[lane] + v1 * a_dst[lane + 64];
#pragma unroll
    for (int off = 32; off; off >>= 1) {
        ps += __shfl_down(ps, off);
        pd += __shfl_down(pd, off);
    }
    if (lane == 0) { als[n] = ps; ald[n] = pd; }
}

// ---------------------------------------------------------------------------
// per-edge attention logit e (leaky-relu), CSR slot order
// ---------------------------------------------------------------------------
template <int H>
__global__ void ecomp_kernel(const int* __restrict__ csrc, const int* __restrict__ cdst,
                             const float* __restrict__ als, const float* __restrict__ ald,
                             float* __restrict__ ebuf, int E) {
    int idx = blockIdx.x * blockDim.x + threadIdx.x;
    if (idx >= E * H) return;
    int slot = idx / H, hd = idx % H;
    float e = als[csrc[slot] * H + hd] + ald[cdst[slot] * H + hd];
    ebuf[idx] = e > 0.f ? e : LEAKY * e;
}

// ---------------------------------------------------------------------------
// Fused segment-softmax + aggregate (online softmax), one block per dst node.
// SPLIT: write bf16 hi/lo (next layer's GEMM A) instead of fp32.
// ---------------------------------------------------------------------------
template <int H, int C, int FPT, bool DO_ELU, bool SPLIT>
__global__ void gat_aggregate_kernel(const float* __restrict__ h, const float* __restrict__ ebuf,
                                     const int* __restrict__ csrc, const int* __restrict__ offs,
                                     const float* __restrict__ als, const float* __restrict__ ald,
                                     const float* __restrict__ bias, float* __restrict__ outp,
                                     unsigned short* __restrict__ ohi, unsigned short* __restrict__ olo,
                                     int N) {
    constexpr int F = H * C;
    constexpr int NT = F / FPT;  // block size
    constexpr int CH = 128;
    __shared__ int sSrc[CH];
    __shared__ float sE[CH * H];
    int n = blockIdx.x;
    int t = threadIdx.x;
    float m[FPT], d[FPT], acc[FPT];
    int f[FPT], hd[FPT];
    const float* selfrow = h + (size_t)n * F;
#pragma unroll
    for (int i = 0; i < FPT; i++) {
        f[i] = t + i * NT;
        hd[i] = f[i] / C;
        float es = als[n * H + hd[i]] + ald[n * H + hd[i]];
        es = es > 0.f ? es : LEAKY * es;
        m[i] = es;
        d[i] = 1.0f;
        acc[i] = selfrow[f[i]];
    }
    int beg = offs[n], end = offs[n + 1];
    for (int base = beg; base < end; base += CH) {
        int len = min(CH, end - base);
        __syncthreads();
        for (int c = t; c < len; c += NT) sSrc[c] = csrc[base + c];
        for (int c = t; c < len * H; c += NT) sE[c] = ebuf[base * H + c];
        __syncthreads();
        for (int c = 0; c < len; c++) {
            int s = sSrc[c];
            const float* srow = h + (size_t)s * F;
#pragma unroll
            for (int i = 0; i < FPT; i++) {
                float e = sE[c * H + hd[i]];
                float nm = fmaxf(m[i], e);
                float sc = __expf(m[i] - nm);
                float p = __expf(e - nm);
                float x = srow[f[i]];
                d[i] = d[i] * sc + p;
                acc[i] = acc[i] * sc + p * x;
                m[i] = nm;
            }
        }
    }
#pragma unroll
    for (int i = 0; i < FPT; i++) {
        float o = acc[i] / (d[i] + EPS_DEN) + bias[f[i]];
        if (DO_ELU) o = o > 0.f ? o : (__expf(o) - 1.0f);
        size_t idx = (size_t)n * F + f[i];
        if (SPLIT) {
            unsigned short hh = f2bf(o);
            ohi[idx] = hh;
            olo[idx] = f2bf(o - bf2f(hh));
        } else {
            outp[idx] = o;
        }
    }
}

// ---------------------------------------------------------------------------
// classifier
// ---------------------------------------------------------------------------
__global__ void classifier_kernel(const float* __restrict__ emb, const float* __restrict__ Wc1,
                                  const float* __restrict__ bc1, const float* __restrict__ Wc2,
                                  const float* __restrict__ bc2, float* __restrict__ out, int N) {
    int wave = threadIdx.x >> 6, lane = threadIdx.x & 63;
    int n = blockIdx.x * 4 + wave;
    if (n >= N) return;
    const float* row = emb + (size_t)n * 128;
    float acc = bc1[lane];
#pragma unroll 4
    for (int k = 0; k < 128; k++) acc += row[k] * Wc1[k * 64 + lane];
    acc = fmaxf(acc, 0.f);
    float o0 = acc * Wc2[lane * 2 + 0];
    float o1 = acc * Wc2[lane * 2 + 1];
#pragma unroll
    for (int off = 32; off; off >>= 1) {
        o0 += __shfl_down(o0, off);
        o1 += __shfl_down(o1, off);
    }
    if (lane == 0) {
        out[n * 2 + 0] = o0 + bc2[0];
        out[n * 2 + 1] = o1 + bc2[1];
    }
}

// ---------------------------------------------------------------------------
extern "C" void kernel_launch(void* const* d_in, const int* in_sizes, int n_in,
                              void* d_out, int out_size, void* d_ws, size_t ws_size,
                              hipStream_t stream) {
    const float* x      = (const float*)d_in[0];
    const int*   ei     = (const int*)d_in[1];
    const float* W1     = (const float*)d_in[2];
    const float* a1s    = (const float*)d_in[3];
    const float* a1d    = (const float*)d_in[4];
    const float* b1     = (const float*)d_in[5];
    const float* W2     = (const float*)d_in[6];
    const float* a2s    = (const float*)d_in[7];
    const float* a2d    = (const float*)d_in[8];
    const float* b2     = (const float*)d_in[9];
    const float* W3     = (const float*)d_in[10];
    const float* a3s    = (const float*)d_in[11];
    const float* a3d    = (const float*)d_in[12];
    const float* b3     = (const float*)d_in[13];
    const float* Wc1    = (const float*)d_in[14];
    const float* bc1    = (const float*)d_in[15];
    const float* Wc2    = (const float*)d_in[16];
    const float* bc2    = (const float*)d_in[17];

    const int N = in_sizes[0] / 256;       // 10000
    const int E = in_sizes[1] / 2;         // 320000
    const int F = 512;

    const int* src = ei;
    const int* dst = ei + E;

    auto align = [](size_t o) { return (o + 255) & ~(size_t)255; };
    size_t o = 0;
    size_t o_G     = o; o = align(o + (size_t)N * F * 4);        // GEMM output h (fp32)
    size_t o_ahi   = o; o = align(o + (size_t)N * F * 2);        // act hi (bf16)
    size_t o_alo   = o; o = align(o + (size_t)N * F * 2);        // act lo
    size_t o_xhi   = o; o = align(o + (size_t)N * 256 * 2);      // x hi
    size_t o_xlo   = o; o = align(o + (size_t)N * 256 * 2);      // x lo
    size_t o_w1h   = o; o = align(o + (size_t)512 * 256 * 2);    // W1^T hi [512,256]
    size_t o_w1l   = o; o = align(o + (size_t)512 * 256 * 2);
    size_t o_w2h   = o; o = align(o + (size_t)512 * 512 * 2);    // W2^T hi [512,512]
    size_t o_w2l   = o; o = align(o + (size_t)512 * 512 * 2);
    size_t o_w3h   = o; o = align(o + (size_t)128 * 512 * 2);    // W3^T hi [128,512]
    size_t o_w3l   = o; o = align(o + (size_t)128 * 512 * 2);
    size_t o_als   = o; o = align(o + (size_t)N * 4 * 4);
    size_t o_ald   = o; o = align(o + (size_t)N * 4 * 4);
    size_t o_cnt   = o; o = align(o + (size_t)N * 4);
    size_t o_off   = o; o = align(o + (size_t)(N + 1) * 4);
    size_t o_csrc  = o; o = align(o + (size_t)E * 4);
    size_t o_cdst  = o; o = align(o + (size_t)E * 4);
    size_t o_ebuf  = o; o = align(o + (size_t)E * 4 * 4);
    (void)ws_size;

    char* ws = (char*)d_ws;
    float* bufG  = (float*)(ws + o_G);
    unsigned short* act_hi = (unsigned short*)(ws + o_ahi);
    unsigned short* act_lo = (unsigned short*)(ws + o_alo);
    unsigned short* x_hi   = (unsigned short*)(ws + o_xhi);
    unsigned short* x_lo   = (unsigned short*)(ws + o_xlo);
    unsigned short* w1h = (unsigned short*)(ws + o_w1h);
    unsigned short* w1l = (unsigned short*)(ws + o_w1l);
    unsigned short* w2h = (unsigned short*)(ws + o_w2h);
    unsigned short* w2l = (unsigned short*)(ws + o_w2l);
    unsigned short* w3h = (unsigned short*)(ws + o_w3h);
    unsigned short* w3l = (unsigned short*)(ws + o_w3l);
    float* als  = (float*)(ws + o_als);
    float* ald  = (float*)(ws + o_ald);
    int*   cnt  = (int*)(ws + o_cnt);
    int*   offs = (int*)(ws + o_off);
    int*   csrc = (int*)(ws + o_csrc);
    int*   cdst = (int*)(ws + o_cdst);
    float* ebuf = (float*)(ws + o_ebuf);

    float* outp = (float*)d_out;                 // [N,2]
    float* emb  = (float*)d_out + (size_t)N * 2; // [N,128]

    // ---- CSR build ----
    hipMemsetAsync(cnt, 0, (size_t)N * 4, stream);
    int eb = (E + 255) / 256;
    hipLaunchKernelGGL(hist_kernel, dim3(eb), dim3(256), 0, stream, dst, cnt, E);
    hipLaunchKernelGGL(scan_kernel, dim3(1), dim3(256), 0, stream, cnt, offs, cnt, N);
    hipLaunchKernelGGL(scatter_kernel, dim3(eb), dim3(256), 0, stream, src, dst, cnt, csrc, cdst, E);

    // ---- splits ----
    hipLaunchKernelGGL(split_kernel, dim3((N * 256 + 255) / 256), dim3(256), 0, stream,
                       x, x_hi, x_lo, N * 256);
    hipLaunchKernelGGL(wsplit_kernel, dim3((256 * 512 + 255) / 256), dim3(256), 0, stream,
                       W1, w1h, w1l, 256, 512);
    hipLaunchKernelGGL(wsplit_kernel, dim3((512 * 512 + 255) / 256), dim3(256), 0, stream,
                       W2, w2h, w2l, 512, 512);
    hipLaunchKernelGGL(wsplit_kernel, dim3((512 * 128 + 255) / 256), dim3(256), 0, stream,
                       W3, w3h, w3l, 512, 128);

    int nb4 = (N + 3) / 4;
    int gy  = (N + 127) / 128;

    // ---- layer 1: x[N,256] @ W1 -> h[N,512] ----
    hipLaunchKernelGGL(mfma_gemm_kernel, dim3(512 / 128, gy), dim3(256), 0, stream,
                       x_hi, x_lo, w1h, w1l, bufG, N, 512, 256);
    hipLaunchKernelGGL(al_h4_kernel, dim3(nb4), dim3(256), 0, stream, bufG, a1s, a1d, als, ald, N);
    hipLaunchKernelGGL((ecomp_kernel<4>), dim3((E * 4 + 255) / 256), dim3(256), 0, stream,
                       csrc, cdst, als, ald, ebuf, E);
    hipLaunchKernelGGL((gat_aggregate_kernel<4, 128, 2, true, true>), dim3(N), dim3(256), 0, stream,
                       bufG, ebuf, csrc, offs, als, ald, b1, (float*)nullptr, act_hi, act_lo, N);

    // ---- layer 2: act[N,512] @ W2 -> h[N,512] ----
    hipLaunchKernelGGL(mfma_gemm_kernel, dim3(512 / 128, gy), dim3(256), 0, stream,
                       act_hi, act_lo, w2h, w2l, bufG, N, 512, 512);
    hipLaunchKernelGGL(al_h4_kernel, dim3(nb4), dim3(256), 0, stream, bufG, a2s, a2d, als, ald, N);
    hipLaunchKernelGGL((ecomp_kernel<4>), dim3((E * 4 + 255) / 256), dim3(256), 0, stream,
                       csrc, cdst, als, ald, ebuf, E);
    hipLaunchKernelGGL((gat_aggregate_kernel<4, 128, 2, true, true>), dim3(N), dim3(256), 0, stream,
                       bufG, ebuf, csrc, offs, als, ald, b2, (float*)nullptr, act_hi, act_lo, N);

    // ---- layer 3: act[N,512] @ W3 -> h[N,128], 1 head, mean==identity, no ELU ----
    hipLaunchKernelGGL(mfma_gemm_kernel, dim3(128 / 128, gy), dim3(256), 0, stream,
                       act_hi, act_lo, w3h, w3l, bufG, N, 128, 512);
    hipLaunchKernelGGL(al_h1_kernel, dim3(nb4), dim3(256), 0, stream, bufG, a3s, a3d, als, ald, N);
    hipLaunchKernelGGL((ecomp_kernel<1>), dim3((E + 255) / 256), dim3(256), 0, stream,
                       csrc, cdst, als, ald, ebuf, E);
    hipLaunchKernelGGL((gat_aggregate_kernel<1, 128, 1, false, false>), dim3(N), dim3(128), 0, stream,
                       bufG, ebuf, csrc, offs, als, ald, b3, emb, (unsigned short*)nullptr,
                       (unsigned short*)nullptr, N);

    // ---- classifier ----
    hipLaunchKernelGGL(classifier_kernel, dim3(nb4), dim3(256), 0, stream,
                       emb, Wc1, bc1, Wc2, bc2, outp, N);
}